// Round 2
// baseline (2003.658 us; speedup 1.0000x reference)
//
#include <hip/hip_runtime.h>
#include <hip/hip_bf16.h>

#define NODE_DIM 256
#define COND_DIM 512
#define OUT_DIM  128
#define HID      64
#define LN_EPS   1e-5f

// ---------------------------------------------------------------------------
// Kernel A: cond projection (weight-normed) -> gamma/beta, plus lin_w norm.
// Blocks 0..B-1: cp[b][o] for o = threadIdx.x (128 threads).
// Block B: normalize lin_w_v rows into wlin (fp32).
// ---------------------------------------------------------------------------
__global__ __launch_bounds__(128) void cond_and_wnorm(
    const float* __restrict__ cond_feats,
    const float* __restrict__ cond_w_v,
    const float* __restrict__ cond_w_g,
    const float* __restrict__ cond_b,
    const float* __restrict__ lin_w_v,
    const float* __restrict__ lin_w_g,
    float* __restrict__ gamma, float* __restrict__ beta,
    float* __restrict__ wlin, int B)
{
    const int o = threadIdx.x;  // 0..127
    if ((int)blockIdx.x == B) {
        // weight-norm lin_w_v row o (length HID)
        float nrm = 0.f;
        float w[HID];
        #pragma unroll
        for (int k = 0; k < HID; ++k) {
            w[k] = lin_w_v[o * HID + k];
            nrm += w[k] * w[k];
        }
        const float s = lin_w_g[o] * rsqrtf(nrm);
        #pragma unroll
        for (int k = 0; k < HID; ++k) wlin[o * HID + k] = w[k] * s;
        return;
    }
    const int b = blockIdx.x;
    float acc = 0.f, nrm = 0.f;
    for (int c = 0; c < COND_DIM; ++c) {
        const float w = cond_w_v[o * COND_DIM + c];
        acc += cond_feats[b * COND_DIM + c] * w;
        nrm += w * w;
    }
    const float cp = cond_w_g[o] * rsqrtf(nrm) * acc + cond_b[o];
    if (o < HID) gamma[b * HID + o] = cp + 1.0f;
    else         beta[b * HID + (o - HID)] = cp;
}

// ---------------------------------------------------------------------------
// Kernel B: per-node FiLM path. One wave (64 threads) per node.
// lane h owns hidden unit h. LN via shfl-xor butterfly across 64 lanes.
// ---------------------------------------------------------------------------
__global__ __launch_bounds__(64) void node_film(
    const float* __restrict__ node_feats,
    const float* __restrict__ film_w,
    const float* __restrict__ film_b,
    const float* __restrict__ lin_b,
    const float* __restrict__ gamma, const float* __restrict__ beta,
    const float* __restrict__ wlin,
    const int*  __restrict__ node2graph,
    float* __restrict__ x_mid, int N)
{
    const int n = blockIdx.x;
    const int h = threadIdx.x;  // 0..63
    __shared__ float sh_feat[NODE_DIM];
    __shared__ float sh_x[HID];

    // stage node feats row (256 fp32 = 1 KiB) into LDS; float4 per lane
    {
        const float4 v = ((const float4*)(node_feats + (size_t)n * NODE_DIM))[h];
        ((float4*)sh_feat)[h] = v;
    }
    __syncthreads();

    // x[h] = dot(node_feats[n], film_w[h]) + film_b[h]
    float acc = film_b[h];
    {
        const float4* wr = (const float4*)(film_w + (size_t)h * NODE_DIM);
        const float4* fv = (const float4*)sh_feat;
        #pragma unroll 8
        for (int i = 0; i < NODE_DIM / 4; ++i) {
            const float4 w = wr[i];
            const float4 f = fv[i];
            acc += f.x * w.x + f.y * w.y + f.z * w.z + f.w * w.w;
        }
    }

    // layernorm over the 64 hidden units (one per lane)
    float s = acc;
    #pragma unroll
    for (int off = 32; off > 0; off >>= 1) s += __shfl_xor(s, off, 64);
    const float mu = s * (1.0f / HID);
    const float d = acc - mu;
    float vs = d * d;
    #pragma unroll
    for (int off = 32; off > 0; off >>= 1) vs += __shfl_xor(vs, off, 64);
    const float inv = rsqrtf(vs * (1.0f / HID) + LN_EPS);

    const int g = node2graph[n];
    float f = gamma[g * HID + h] * (d * inv) + beta[g * HID + h];
    f = fmaxf(f, 0.f);
    sh_x[h] = f;
    __syncthreads();

    // y = x @ wlin.T + lin_b ; lane h computes outputs h and h+64
    float acc0 = lin_b[h];
    float acc1 = lin_b[h + HID];
    {
        const float4* xv = (const float4*)sh_x;
        const float4* w0 = (const float4*)(wlin + (size_t)h * HID);
        const float4* w1 = (const float4*)(wlin + (size_t)(h + HID) * HID);
        #pragma unroll
        for (int i = 0; i < HID / 4; ++i) {
            const float4 xx = xv[i];
            const float4 a = w0[i];
            const float4 b = w1[i];
            acc0 += xx.x * a.x + xx.y * a.y + xx.z * a.z + xx.w * a.w;
            acc1 += xx.x * b.x + xx.y * b.y + xx.z * b.z + xx.w * b.w;
        }
    }
    float* outrow = x_mid + (size_t)n * OUT_DIM;
    outrow[h]       = acc0;
    outrow[h + HID] = acc1;
}

// ---------------------------------------------------------------------------
// Kernel C: edge scatter-add. 2 edges per 256-thread block, 128 feat threads
// per edge. Coalesced gather of x_mid[src] row + fp32 atomics into agg[dst].
// ---------------------------------------------------------------------------
__global__ __launch_bounds__(256) void edge_scatter(
    const int* __restrict__ edge_index,
    const float* __restrict__ x_mid,
    float* __restrict__ agg, float* __restrict__ cnt, int E)
{
    const int eid = blockIdx.x * 2 + (threadIdx.x >> 7);
    const int f = threadIdx.x & 127;
    if (eid >= E) return;
    const int src = edge_index[eid];
    const int dst = edge_index[E + eid];
    const float v = x_mid[(size_t)src * OUT_DIM + f];
    atomicAdd(&agg[(size_t)dst * OUT_DIM + f], v);
    if (f == 0) atomicAdd(&cnt[dst], 1.0f);
}

// ---------------------------------------------------------------------------
// Kernel D: mean + relu + fp32 store
// ---------------------------------------------------------------------------
__global__ __launch_bounds__(256) void finalize(
    const float* __restrict__ agg, const float* __restrict__ cnt,
    float* __restrict__ out, int total)
{
    const int i = blockIdx.x * 256 + threadIdx.x;
    if (i >= total) return;
    const int n = i >> 7;  // /OUT_DIM
    const float c = fmaxf(cnt[n], 1.0f);
    const float v = agg[i] / c;
    out[i] = fmaxf(v, 0.f);
}

extern "C" void kernel_launch(void* const* d_in, const int* in_sizes, int n_in,
                              void* d_out, int out_size, void* d_ws, size_t ws_size,
                              hipStream_t stream) {
    const float* node_feats = (const float*)d_in[0];
    const float* cond_feats = (const float*)d_in[1];
    const float* cond_w_v   = (const float*)d_in[2];
    const float* cond_w_g   = (const float*)d_in[3];
    const float* cond_b     = (const float*)d_in[4];
    const float* film_w     = (const float*)d_in[5];
    const float* film_b     = (const float*)d_in[6];
    const float* lin_w_v    = (const float*)d_in[7];
    const float* lin_w_g    = (const float*)d_in[8];
    const float* lin_b      = (const float*)d_in[9];
    const int* edge_index   = (const int*)d_in[10];
    const int* node2graph   = (const int*)d_in[11];

    const int N = in_sizes[0] / NODE_DIM;     // 100000
    const int B = in_sizes[1] / COND_DIM;     // 64
    const int E = in_sizes[10] / 2;           // 1600000

    // workspace layout (fp32):
    //   agg   : N*OUT_DIM   (zeroed)
    //   cnt   : N           (zeroed)
    //   x_mid : N*OUT_DIM
    //   gamma : B*HID, beta : B*HID, wlin : OUT_DIM*HID
    char* ws = (char*)d_ws;
    size_t off = 0;
    float* agg = (float*)(ws + off);   off += (size_t)N * OUT_DIM * 4;
    float* cnt = (float*)(ws + off);   off += (size_t)N * 4;
    const size_t zero_bytes = off;     // agg + cnt zeroed together
    float* x_mid = (float*)(ws + off); off += (size_t)N * OUT_DIM * 4;
    float* gamma = (float*)(ws + off); off += (size_t)B * HID * 4;
    float* beta  = (float*)(ws + off); off += (size_t)B * HID * 4;
    float* wlin  = (float*)(ws + off); off += (size_t)OUT_DIM * HID * 4;

    hipMemsetAsync(d_ws, 0, zero_bytes, stream);

    cond_and_wnorm<<<B + 1, 128, 0, stream>>>(
        cond_feats, cond_w_v, cond_w_g, cond_b, lin_w_v, lin_w_g,
        gamma, beta, wlin, B);

    node_film<<<N, 64, 0, stream>>>(
        node_feats, film_w, film_b, lin_b, gamma, beta, wlin, node2graph,
        x_mid, N);

    edge_scatter<<<(E + 1) / 2, 256, 0, stream>>>(
        edge_index, x_mid, agg, cnt, E);

    const int total = N * OUT_DIM;
    finalize<<<(total + 255) / 256, 256, 0, stream>>>(agg, cnt,
        (float*)d_out, total);
}

// Round 3
// 628.918 us; speedup vs baseline: 3.1859x; 3.1859x over previous
//
#include <hip/hip_runtime.h>
#include <hip/hip_bf16.h>

#define NODE_DIM 256
#define COND_DIM 512
#define OUT_DIM  128
#define HID      64
#define LN_EPS   1e-5f
#define TN       256   // nodes per block in node_film_ws
#define KC       32    // k-chunk of feats
#define LDSS     37    // padded LDS row stride (conflict-free: 37%32=5 coprime 32)

// ---------------------------------------------------------------------------
// Kernel A (grid 130 x 256):
//  blocks 0..127  : cond projection output o = blockIdx.x (weight-normed)
//  block 128      : weight-norm lin_w_v rows -> wlin
//  block 129      : transpose film_w [64,256] -> fwT [256,64]
// ---------------------------------------------------------------------------
__global__ __launch_bounds__(256) void prep(
    const float* __restrict__ cond_feats,
    const float* __restrict__ cond_w_v,
    const float* __restrict__ cond_w_g,
    const float* __restrict__ cond_b,
    const float* __restrict__ lin_w_v,
    const float* __restrict__ lin_w_g,
    const float* __restrict__ film_w,
    float* __restrict__ gamma, float* __restrict__ beta,
    float* __restrict__ wlin, float* __restrict__ fwT, int B)
{
    const int t = threadIdx.x;
    const int bid = blockIdx.x;
    if (bid == 128) {
        if (t < OUT_DIM) {
            const int o = t;
            float nrm = 0.f;
            float w[HID];
            #pragma unroll
            for (int k = 0; k < HID; ++k) {
                w[k] = lin_w_v[o * HID + k];
                nrm += w[k] * w[k];
            }
            const float s = lin_w_g[o] * rsqrtf(nrm);
            #pragma unroll
            for (int k = 0; k < HID; ++k) wlin[o * HID + k] = w[k] * s;
        }
        return;
    }
    if (bid == 129) {
        // fwT[k*64 + h] = film_w[h*256 + k]
        for (int idx = t; idx < HID * NODE_DIM; idx += 256) {
            const int h = idx & (HID - 1);
            const int k = idx >> 6;
            fwT[k * HID + h] = film_w[h * NODE_DIM + k];
        }
        return;
    }
    // cond projection, output o
    const int o = bid;
    const int lane = t & 63;
    const int wv = t >> 6;  // wave id 0..3
    __shared__ float s_cp[64];
    __shared__ float s_nrm;
    float wreg[COND_DIM / 64];
    #pragma unroll
    for (int j = 0; j < COND_DIM / 64; ++j)
        wreg[j] = cond_w_v[o * COND_DIM + j * 64 + lane];
    // nrm (each wave computes same; wave 0 publishes)
    float nr = 0.f;
    #pragma unroll
    for (int j = 0; j < COND_DIM / 64; ++j) nr += wreg[j] * wreg[j];
    #pragma unroll
    for (int off = 32; off > 0; off >>= 1) nr += __shfl_xor(nr, off, 64);
    if (t == 0) s_nrm = nr;
    for (int b = wv; b < 64; b += 4) {
        float a = 0.f;
        #pragma unroll
        for (int j = 0; j < COND_DIM / 64; ++j)
            a += wreg[j] * cond_feats[b * COND_DIM + j * 64 + lane];
        #pragma unroll
        for (int off = 32; off > 0; off >>= 1) a += __shfl_xor(a, off, 64);
        if (lane == 0) s_cp[b] = a;
    }
    __syncthreads();
    if (t < 64) {
        const float scale = cond_w_g[o] * rsqrtf(s_nrm);
        const float cp = scale * s_cp[t] + cond_b[o];
        if (o < HID) gamma[t * HID + o] = cp + 1.0f;
        else         beta[t * HID + (o - HID)] = cp;
    }
}

// ---------------------------------------------------------------------------
// Kernel B: node FiLM path, weight-stationary, one node per thread.
// ---------------------------------------------------------------------------
__global__ __launch_bounds__(256) void node_film_ws(
    const float* __restrict__ nf,
    const float* __restrict__ fwT,      // [256 k][64 h]
    const float* __restrict__ film_b,
    const float* __restrict__ lin_b,
    const float* __restrict__ gamma, const float* __restrict__ beta,
    const float* __restrict__ wlin,     // [128 o][64 h]
    const int*  __restrict__ n2g,
    float* __restrict__ x_mid, int N)
{
    const int t = threadIdx.x;
    const int n0 = blockIdx.x * TN;
    __shared__ float sh[TN * LDSS];   // 37888 B
    float acc[HID];
    #pragma unroll
    for (int h = 0; h < HID; ++h) acc[h] = 0.f;

    #pragma unroll 1
    for (int kc = 0; kc < NODE_DIM / KC; ++kc) {
        __syncthreads();
        // cooperative coalesced load: 2048 float4, 8 per thread
        #pragma unroll
        for (int j = 0; j < 8; ++j) {
            const int fidx = j * 256 + t;
            const int row = fidx >> 3;      // 8 float4 per row
            const int c4  = fidx & 7;
            int nn = n0 + row; if (nn >= N) nn = N - 1;
            const float4 v = *(const float4*)(nf + (size_t)nn * NODE_DIM + kc * KC + c4 * 4);
            float* d = &sh[row * LDSS + c4 * 4];
            d[0] = v.x; d[1] = v.y; d[2] = v.z; d[3] = v.w;
        }
        __syncthreads();
        #pragma unroll 1
        for (int k = 0; k < KC; ++k) {
            const float f = sh[t * LDSS + k];
            const float4* wt = (const float4*)(fwT + ((kc * KC + k) << 6));
            #pragma unroll
            for (int q = 0; q < 16; ++q) {
                const float4 wq = wt[q];
                acc[4 * q + 0] += f * wq.x;
                acc[4 * q + 1] += f * wq.y;
                acc[4 * q + 2] += f * wq.z;
                acc[4 * q + 3] += f * wq.w;
            }
        }
    }

    // + film bias, layernorm (register-local), FiLM, relu
    {
        const float4* fb4 = (const float4*)film_b;
        #pragma unroll
        for (int q = 0; q < 16; ++q) {
            const float4 b4 = fb4[q];
            acc[4 * q + 0] += b4.x; acc[4 * q + 1] += b4.y;
            acc[4 * q + 2] += b4.z; acc[4 * q + 3] += b4.w;
        }
    }
    float mu = 0.f;
    #pragma unroll
    for (int h = 0; h < HID; ++h) mu += acc[h];
    mu *= (1.0f / HID);
    float var = 0.f;
    #pragma unroll
    for (int h = 0; h < HID; ++h) { const float d = acc[h] - mu; var += d * d; }
    const float inv = rsqrtf(var * (1.0f / HID) + LN_EPS);
    {
        int nn = n0 + t; if (nn >= N) nn = N - 1;
        const int g = n2g[nn];
        const float4* ga = (const float4*)(gamma + (g << 6));
        const float4* be = (const float4*)(beta + (g << 6));
        #pragma unroll
        for (int q = 0; q < 16; ++q) {
            const float4 gq = ga[q], bq = be[q];
            acc[4 * q + 0] = fmaxf(gq.x * ((acc[4 * q + 0] - mu) * inv) + bq.x, 0.f);
            acc[4 * q + 1] = fmaxf(gq.y * ((acc[4 * q + 1] - mu) * inv) + bq.y, 0.f);
            acc[4 * q + 2] = fmaxf(gq.z * ((acc[4 * q + 2] - mu) * inv) + bq.z, 0.f);
            acc[4 * q + 3] = fmaxf(gq.w * ((acc[4 * q + 3] - mu) * inv) + bq.w, 0.f);
        }
    }

    // second linear: 8 chunks of 16 outputs; LDS transpose for coalesced stores
    #pragma unroll 1
    for (int oc = 0; oc < OUT_DIM / 16; ++oc) {
        float o16[16];
        #pragma unroll
        for (int oo = 0; oo < 16; ++oo) {
            const int o = oc * 16 + oo;
            const float4* wr = (const float4*)(wlin + (o << 6));
            float s = lin_b[o];
            #pragma unroll
            for (int q = 0; q < 16; ++q) {
                const float4 wq = wr[q];
                s += acc[4 * q + 0] * wq.x + acc[4 * q + 1] * wq.y
                   + acc[4 * q + 2] * wq.z + acc[4 * q + 3] * wq.w;
            }
            o16[oo] = s;
        }
        __syncthreads();
        #pragma unroll
        for (int oo = 0; oo < 16; ++oo) sh[t * 17 + oo] = o16[oo];
        __syncthreads();
        #pragma unroll
        for (int j = 0; j < 16; ++j) {
            const int idx = j * 256 + t;
            const int row = idx >> 4, c = idx & 15;
            const int nn = n0 + row;
            if (nn < N) x_mid[(size_t)nn * OUT_DIM + oc * 16 + c] = sh[row * 17 + c];
        }
    }
}

// ---------------------------------------------------------------------------
// CSR build: degree histogram, 3-step scan, bucket fill
// ---------------------------------------------------------------------------
__global__ __launch_bounds__(256) void deg_count(
    const int* __restrict__ ei, int* __restrict__ deg, int E)
{
    const int e = blockIdx.x * 256 + threadIdx.x;
    if (e < E) atomicAdd(&deg[ei[E + e]], 1);
}

__global__ __launch_bounds__(1024) void scan1(
    const int* __restrict__ deg, int* __restrict__ csr_off,
    int* __restrict__ bsums, int N)
{
    __shared__ int s[1024];
    const int t = threadIdx.x;
    const int i = blockIdx.x * 1024 + t;
    s[t] = (i < N) ? deg[i] : 0;
    __syncthreads();
    for (int off = 1; off < 1024; off <<= 1) {
        const int x = s[t];
        const int y = (t >= off) ? s[t - off] : 0;
        __syncthreads();
        s[t] = x + y;
        __syncthreads();
    }
    if (i < N) csr_off[i + 1] = s[t];
    if (t == 1023) bsums[blockIdx.x] = s[1023];
}

__global__ __launch_bounds__(1024) void scan2(
    const int* __restrict__ bsums, int* __restrict__ boff, int NB)
{
    __shared__ int s[1024];
    const int t = threadIdx.x;
    const int v = (t < NB) ? bsums[t] : 0;
    s[t] = v;
    __syncthreads();
    for (int off = 1; off < 1024; off <<= 1) {
        const int x = s[t];
        const int y = (t >= off) ? s[t - off] : 0;
        __syncthreads();
        s[t] = x + y;
        __syncthreads();
    }
    if (t < NB) boff[t] = s[t] - v;  // exclusive
}

__global__ __launch_bounds__(1024) void scan3(
    int* __restrict__ csr_off, const int* __restrict__ boff, int N)
{
    const int i = blockIdx.x * 1024 + threadIdx.x;
    if (i < N) csr_off[i + 1] += boff[blockIdx.x];
    if (i == 0) csr_off[0] = 0;
}

__global__ __launch_bounds__(256) void bucket_fill(
    const int* __restrict__ ei, const int* __restrict__ csr_off,
    int* __restrict__ cursor, int* __restrict__ bucket_src, int E)
{
    const int e = blockIdx.x * 256 + threadIdx.x;
    if (e >= E) return;
    const int src = ei[e];
    const int dst = ei[E + e];
    const int pos = atomicAdd(&cursor[dst], 1);
    bucket_src[csr_off[dst] + pos] = src;
}

// ---------------------------------------------------------------------------
// Kernel C: gather-reduce per dst node (no float atomics), fused mean+relu.
// One block (128 threads) per dst; thread f owns feature f.
// ---------------------------------------------------------------------------
__global__ __launch_bounds__(128) void edge_aggregate(
    const int* __restrict__ csr_off, const int* __restrict__ bucket_src,
    const float* __restrict__ x_mid, float* __restrict__ out)
{
    const int dst = blockIdx.x;
    const int t = threadIdx.x;
    const int base = csr_off[dst];
    const int end  = csr_off[dst + 1];
    __shared__ int s_src[128];
    float a0 = 0.f, a1 = 0.f, a2 = 0.f, a3 = 0.f;
    for (int p = base; p < end; p += 128) {
        const int m = min(128, end - p);
        __syncthreads();
        if (t < m) s_src[t] = bucket_src[p + t];
        __syncthreads();
        int i = 0;
        for (; i + 4 <= m; i += 4) {
            a0 += x_mid[(size_t)s_src[i + 0] * OUT_DIM + t];
            a1 += x_mid[(size_t)s_src[i + 1] * OUT_DIM + t];
            a2 += x_mid[(size_t)s_src[i + 2] * OUT_DIM + t];
            a3 += x_mid[(size_t)s_src[i + 3] * OUT_DIM + t];
        }
        for (; i < m; ++i) a0 += x_mid[(size_t)s_src[i] * OUT_DIM + t];
    }
    const float s = (a0 + a1) + (a2 + a3);
    const int deg = end - base;
    out[(size_t)dst * OUT_DIM + t] = fmaxf(s / fmaxf((float)deg, 1.f), 0.f);
}

extern "C" void kernel_launch(void* const* d_in, const int* in_sizes, int n_in,
                              void* d_out, int out_size, void* d_ws, size_t ws_size,
                              hipStream_t stream) {
    const float* node_feats = (const float*)d_in[0];
    const float* cond_feats = (const float*)d_in[1];
    const float* cond_w_v   = (const float*)d_in[2];
    const float* cond_w_g   = (const float*)d_in[3];
    const float* cond_b     = (const float*)d_in[4];
    const float* film_w     = (const float*)d_in[5];
    const float* film_b     = (const float*)d_in[6];
    const float* lin_w_v    = (const float*)d_in[7];
    const float* lin_w_g    = (const float*)d_in[8];
    const float* lin_b      = (const float*)d_in[9];
    const int* edge_index   = (const int*)d_in[10];
    const int* node2graph   = (const int*)d_in[11];

    const int N = in_sizes[0] / NODE_DIM;     // 100000
    const int B = in_sizes[1] / COND_DIM;     // 64
    const int E = in_sizes[10] / 2;           // 1600000
    const int NB = (N + 1023) / 1024;         // scan blocks (<=1024 assumed)

    auto align_up = [](size_t x) { return (x + 255) & ~(size_t)255; };
    char* ws = (char*)d_ws;
    size_t off = 0;
    int* deg        = (int*)(ws + off); off += align_up((size_t)N * 4);
    int* cursor     = (int*)(ws + off); off += align_up((size_t)N * 4);
    const size_t zero_bytes = off;            // deg + cursor zeroed
    int* csr_off    = (int*)(ws + off); off += align_up((size_t)(N + 1) * 4);
    int* bsums      = (int*)(ws + off); off += align_up(1024 * 4);
    int* boff       = (int*)(ws + off); off += align_up(1024 * 4);
    int* bucket_src = (int*)(ws + off); off += align_up((size_t)E * 4);
    float* x_mid    = (float*)(ws + off); off += align_up((size_t)N * OUT_DIM * 4);
    float* gamma    = (float*)(ws + off); off += align_up((size_t)B * HID * 4);
    float* beta     = (float*)(ws + off); off += align_up((size_t)B * HID * 4);
    float* wlin     = (float*)(ws + off); off += align_up((size_t)OUT_DIM * HID * 4);
    float* fwT      = (float*)(ws + off); off += align_up((size_t)NODE_DIM * HID * 4);

    hipMemsetAsync(d_ws, 0, zero_bytes, stream);

    prep<<<130, 256, 0, stream>>>(cond_feats, cond_w_v, cond_w_g, cond_b,
                                  lin_w_v, lin_w_g, film_w,
                                  gamma, beta, wlin, fwT, B);

    deg_count<<<(E + 255) / 256, 256, 0, stream>>>(edge_index, deg, E);
    scan1<<<NB, 1024, 0, stream>>>(deg, csr_off, bsums, N);
    scan2<<<1, 1024, 0, stream>>>(bsums, boff, NB);
    scan3<<<NB, 1024, 0, stream>>>(csr_off, boff, N);
    bucket_fill<<<(E + 255) / 256, 256, 0, stream>>>(edge_index, csr_off,
                                                     cursor, bucket_src, E);

    node_film_ws<<<(N + TN - 1) / TN, 256, 0, stream>>>(
        node_feats, fwT, film_b, lin_b, gamma, beta, wlin, node2graph,
        x_mid, N);

    edge_aggregate<<<N, 128, 0, stream>>>(csr_off, bucket_src, x_mid,
                                          (float*)d_out);
}

// Round 4
// 491.592 us; speedup vs baseline: 4.0759x; 1.2793x over previous
//
#include <hip/hip_runtime.h>
#include <hip/hip_bf16.h>

#define NODE_DIM 256
#define COND_DIM 512
#define OUT_DIM  128
#define HID      64
#define LN_EPS   1e-5f

typedef __attribute__((ext_vector_type(8))) short bf16x8;
typedef __attribute__((ext_vector_type(4))) float f32x4;

__device__ __forceinline__ short f2bf(float f) {
    __hip_bfloat16 h = __float2bfloat16(f);
    return *reinterpret_cast<short*>(&h);
}
__device__ __forceinline__ float bf_lo(unsigned int v) {
    union { unsigned int u; float f; } x; x.u = v << 16; return x.f;
}
__device__ __forceinline__ float bf_hi(unsigned int v) {
    union { unsigned int u; float f; } x; x.u = v & 0xffff0000u; return x.f;
}

// ---------------------------------------------------------------------------
// prep (grid 130 x 256):
//  blocks 0..127 : cond projection output o (weight-normed) -> gamma/beta
//  block 128     : weight-norm lin_w_v rows -> wlin_bf [128][64] bf16
//  block 129     : film_w -> film_w_bf [64][256] bf16 (same layout; B-operand
//                  wants [n][k] row-major, which film_w already is)
// ---------------------------------------------------------------------------
__global__ __launch_bounds__(256) void prep(
    const float* __restrict__ cond_feats,
    const float* __restrict__ cond_w_v,
    const float* __restrict__ cond_w_g,
    const float* __restrict__ cond_b,
    const float* __restrict__ lin_w_v,
    const float* __restrict__ lin_w_g,
    const float* __restrict__ film_w,
    float* __restrict__ gamma, float* __restrict__ beta,
    short* __restrict__ wlin_bf, short* __restrict__ fw_bf, int B)
{
    const int t = threadIdx.x;
    const int bid = blockIdx.x;
    if (bid == 128) {
        if (t < OUT_DIM) {
            const int o = t;
            float nrm = 0.f;
            float w[HID];
            #pragma unroll
            for (int k = 0; k < HID; ++k) {
                w[k] = lin_w_v[o * HID + k];
                nrm += w[k] * w[k];
            }
            const float s = lin_w_g[o] * rsqrtf(nrm);
            #pragma unroll
            for (int k = 0; k < HID; ++k) wlin_bf[o * HID + k] = f2bf(w[k] * s);
        }
        return;
    }
    if (bid == 129) {
        for (int idx = t; idx < HID * NODE_DIM; idx += 256)
            fw_bf[idx] = f2bf(film_w[idx]);
        return;
    }
    // cond projection, output o = bid
    const int o = bid;
    const int lane = t & 63;
    const int wv = t >> 6;
    __shared__ float s_cp[64];
    __shared__ float s_nrm;
    float wreg[COND_DIM / 64];
    #pragma unroll
    for (int j = 0; j < COND_DIM / 64; ++j)
        wreg[j] = cond_w_v[o * COND_DIM + j * 64 + lane];
    float nr = 0.f;
    #pragma unroll
    for (int j = 0; j < COND_DIM / 64; ++j) nr += wreg[j] * wreg[j];
    #pragma unroll
    for (int off = 32; off > 0; off >>= 1) nr += __shfl_xor(nr, off, 64);
    if (t == 0) s_nrm = nr;
    for (int b = wv; b < 64; b += 4) {
        float a = 0.f;
        #pragma unroll
        for (int j = 0; j < COND_DIM / 64; ++j)
            a += wreg[j] * cond_feats[b * COND_DIM + j * 64 + lane];
        #pragma unroll
        for (int off = 32; off > 0; off >>= 1) a += __shfl_xor(a, off, 64);
        if (lane == 0) s_cp[b] = a;
    }
    __syncthreads();
    if (t < 64) {
        const float scale = cond_w_g[o] * rsqrtf(s_nrm);
        const float cp = scale * s_cp[t] + cond_b[o];
        if (o < HID) gamma[t * HID + o] = cp + 1.0f;
        else         beta[t * HID + (o - HID)] = cp;
    }
}

// ---------------------------------------------------------------------------
// node path via MFMA. Block = 256 thr = 4 waves; wave w owns 16-node strip.
// GEMM1 [64x256]@[256x64] -> LN/FiLM/relu in-register -> LDS (C->A layout
// transform) -> GEMM2 [64x64]@[64x128] -> bf16 x_mid store.
// Layouts (HW-verified): A/B frag [lane&15][quad*8+j]; C/D col=lane&15,
// row=quad*4+reg.
// ---------------------------------------------------------------------------
__global__ __launch_bounds__(256) void node_film_mfma(
    const float* __restrict__ nf,
    const short* __restrict__ fw_bf,      // [64 h][256 k]
    const float* __restrict__ film_b,
    const float* __restrict__ lin_b,
    const float* __restrict__ gamma, const float* __restrict__ beta,
    const short* __restrict__ wlin_bf,    // [128 o][64 h]
    const int*  __restrict__ n2g,
    unsigned short* __restrict__ x_mid,   // [N][128] bf16
    int N)
{
    const int tid = threadIdx.x;
    const int w = tid >> 6;
    const int lane = tid & 63;
    const int c = lane & 15;
    const int quad = lane >> 4;
    const int n0 = blockIdx.x * 64;

    __shared__ float xt[64 * 65];   // 16.6 KB, stride 65 (conflict-light)

    // ---- GEMM1: C1[m=16 nodes][n=64 hid], K=256 in 8 steps of 32
    f32x4 c1[4];
    #pragma unroll
    for (int t = 0; t < 4; ++t) { c1[t][0]=0.f; c1[t][1]=0.f; c1[t][2]=0.f; c1[t][3]=0.f; }

    const int mnode = n0 + w * 16 + c;
    const int arow = (mnode < N) ? mnode : (N - 1);
    const float* aptr = nf + (size_t)arow * NODE_DIM + quad * 8;

    #pragma unroll 2
    for (int k0 = 0; k0 < NODE_DIM; k0 += 32) {
        const float4 a01 = *(const float4*)(aptr + k0);
        const float4 a23 = *(const float4*)(aptr + k0 + 4);
        bf16x8 af;
        af[0]=f2bf(a01.x); af[1]=f2bf(a01.y); af[2]=f2bf(a01.z); af[3]=f2bf(a01.w);
        af[4]=f2bf(a23.x); af[5]=f2bf(a23.y); af[6]=f2bf(a23.z); af[7]=f2bf(a23.w);
        #pragma unroll
        for (int nt = 0; nt < 4; ++nt) {
            const bf16x8 bfr = *(const bf16x8*)(fw_bf + ((nt * 16 + c) * NODE_DIM + k0 + quad * 8));
            c1[nt] = __builtin_amdgcn_mfma_f32_16x16x32_bf16(af, bfr, c1[nt], 0, 0, 0);
        }
    }

    // + film bias (per col n = nt*16 + c)
    #pragma unroll
    for (int nt = 0; nt < 4; ++nt) {
        const float b = film_b[nt * 16 + c];
        c1[nt][0] += b; c1[nt][1] += b; c1[nt][2] += b; c1[nt][3] += b;
    }

    // LN per row (node): row = quad*4 + r; cols spread over 16 lanes x 4 tiles
    float sum[4], sq[4];
    #pragma unroll
    for (int r = 0; r < 4; ++r) {
        sum[r] = c1[0][r] + c1[1][r] + c1[2][r] + c1[3][r];
        sq[r]  = c1[0][r]*c1[0][r] + c1[1][r]*c1[1][r]
               + c1[2][r]*c1[2][r] + c1[3][r]*c1[3][r];
    }
    #pragma unroll
    for (int off = 1; off < 16; off <<= 1) {
        #pragma unroll
        for (int r = 0; r < 4; ++r) {
            sum[r] += __shfl_xor(sum[r], off, 64);
            sq[r]  += __shfl_xor(sq[r],  off, 64);
        }
    }
    float mu[4], inv[4];
    int gid[4];
    #pragma unroll
    for (int r = 0; r < 4; ++r) {
        mu[r] = sum[r] * (1.0f / HID);
        float var = sq[r] * (1.0f / HID) - mu[r] * mu[r];
        var = fmaxf(var, 0.f);
        inv[r] = rsqrtf(var + LN_EPS);
        const int nn = n0 + w * 16 + quad * 4 + r;
        gid[r] = n2g[(nn < N) ? nn : (N - 1)];
    }

    // FiLM + relu -> LDS x tile (fp32), row = local node, col = hid
    #pragma unroll
    for (int r = 0; r < 4; ++r) {
        const int row = w * 16 + quad * 4 + r;
        #pragma unroll
        for (int nt = 0; nt < 4; ++nt) {
            const int col = nt * 16 + c;
            const float ga = gamma[gid[r] * HID + col];
            const float be = beta[gid[r] * HID + col];
            float v = ga * ((c1[nt][r] - mu[r]) * inv[r]) + be;
            xt[row * 65 + col] = fmaxf(v, 0.f);
        }
    }
    __syncthreads();

    // ---- GEMM2: C2[m=16 nodes][n=128 out], K=64 in 2 steps of 32
    f32x4 c2[8];
    #pragma unroll
    for (int t = 0; t < 8; ++t) { c2[t][0]=0.f; c2[t][1]=0.f; c2[t][2]=0.f; c2[t][3]=0.f; }

    const int am = w * 16 + c;   // A row (local node)
    #pragma unroll
    for (int kt = 0; kt < 2; ++kt) {
        const float* xp = xt + am * 65 + kt * 32 + quad * 8;
        bf16x8 af;
        #pragma unroll
        for (int j = 0; j < 8; ++j) af[j] = f2bf(xp[j]);
        #pragma unroll
        for (int nt = 0; nt < 8; ++nt) {
            const bf16x8 bfr = *(const bf16x8*)(wlin_bf + (nt * 16 + c) * HID + kt * 32 + quad * 8);
            c2[nt] = __builtin_amdgcn_mfma_f32_16x16x32_bf16(af, bfr, c2[nt], 0, 0, 0);
        }
    }

    // + lin bias, store bf16
    #pragma unroll
    for (int nt = 0; nt < 8; ++nt) {
        const float lb = lin_b[nt * 16 + c];
        #pragma unroll
        for (int r = 0; r < 4; ++r) {
            const int nn = n0 + w * 16 + quad * 4 + r;
            if (nn < N) {
                const short b = f2bf(c2[nt][r] + lb);
                x_mid[(size_t)nn * OUT_DIM + nt * 16 + c] = (unsigned short)b;
            }
        }
    }
}

// ---------------------------------------------------------------------------
// CSR build: degree histogram, 3-step scan, bucket fill
// ---------------------------------------------------------------------------
__global__ __launch_bounds__(256) void deg_count(
    const int* __restrict__ ei, int* __restrict__ deg, int E)
{
    const int e = blockIdx.x * 256 + threadIdx.x;
    if (e < E) atomicAdd(&deg[ei[E + e]], 1);
}

__global__ __launch_bounds__(1024) void scan1(
    const int* __restrict__ deg, int* __restrict__ csr_off,
    int* __restrict__ bsums, int N)
{
    __shared__ int s[1024];
    const int t = threadIdx.x;
    const int i = blockIdx.x * 1024 + t;
    s[t] = (i < N) ? deg[i] : 0;
    __syncthreads();
    for (int off = 1; off < 1024; off <<= 1) {
        const int x = s[t];
        const int y = (t >= off) ? s[t - off] : 0;
        __syncthreads();
        s[t] = x + y;
        __syncthreads();
    }
    if (i < N) csr_off[i + 1] = s[t];
    if (t == 1023) bsums[blockIdx.x] = s[1023];
}

__global__ __launch_bounds__(1024) void scan2(
    const int* __restrict__ bsums, int* __restrict__ boff, int NB)
{
    __shared__ int s[1024];
    const int t = threadIdx.x;
    const int v = (t < NB) ? bsums[t] : 0;
    s[t] = v;
    __syncthreads();
    for (int off = 1; off < 1024; off <<= 1) {
        const int x = s[t];
        const int y = (t >= off) ? s[t - off] : 0;
        __syncthreads();
        s[t] = x + y;
        __syncthreads();
    }
    if (t < NB) boff[t] = s[t] - v;  // exclusive
}

__global__ __launch_bounds__(1024) void scan3(
    int* __restrict__ csr_off, const int* __restrict__ boff, int N)
{
    const int i = blockIdx.x * 1024 + threadIdx.x;
    if (i < N) csr_off[i + 1] += boff[blockIdx.x];
    if (i == 0) csr_off[0] = 0;
}

__global__ __launch_bounds__(256) void bucket_fill(
    const int* __restrict__ ei, const int* __restrict__ csr_off,
    int* __restrict__ cursor, int* __restrict__ bucket_src, int E)
{
    const int e = blockIdx.x * 256 + threadIdx.x;
    if (e >= E) return;
    const int src = ei[e];
    const int dst = ei[E + e];
    const int pos = atomicAdd(&cursor[dst], 1);
    bucket_src[csr_off[dst] + pos] = src;
}

// ---------------------------------------------------------------------------
// gather-reduce, wave per dst node. Lane owns features {2*lane, 2*lane+1}
// (one packed bf16 pair = 4B -> 256B coalesced row reads). Fused mean+relu.
// ---------------------------------------------------------------------------
__global__ __launch_bounds__(256) void edge_aggregate(
    const int* __restrict__ csr_off, const int* __restrict__ bucket_src,
    const unsigned short* __restrict__ xm, float* __restrict__ out, int N)
{
    const int dst = blockIdx.x * 4 + (threadIdx.x >> 6);
    const int lane = threadIdx.x & 63;
    if (dst >= N) return;
    const int base = csr_off[dst];
    const int end  = csr_off[dst + 1];
    float a0 = 0.f, a1 = 0.f;
    for (int p = base; p < end; p += 64) {
        const int m = min(64, end - p);
        const int s = bucket_src[p + ((lane < m) ? lane : 0)];
        #pragma unroll 4
        for (int i = 0; i < m; ++i) {
            const int src = __shfl(s, i, 64);
            const unsigned int v = *(const unsigned int*)(xm + (size_t)src * OUT_DIM + lane * 2);
            a0 += bf_lo(v);
            a1 += bf_hi(v);
        }
    }
    const float d = fmaxf((float)(end - base), 1.f);
    float2 o;
    o.x = fmaxf(a0 / d, 0.f);
    o.y = fmaxf(a1 / d, 0.f);
    *(float2*)(out + (size_t)dst * OUT_DIM + lane * 2) = o;
}

extern "C" void kernel_launch(void* const* d_in, const int* in_sizes, int n_in,
                              void* d_out, int out_size, void* d_ws, size_t ws_size,
                              hipStream_t stream) {
    const float* node_feats = (const float*)d_in[0];
    const float* cond_feats = (const float*)d_in[1];
    const float* cond_w_v   = (const float*)d_in[2];
    const float* cond_w_g   = (const float*)d_in[3];
    const float* cond_b     = (const float*)d_in[4];
    const float* film_w     = (const float*)d_in[5];
    const float* film_b     = (const float*)d_in[6];
    const float* lin_w_v    = (const float*)d_in[7];
    const float* lin_w_g    = (const float*)d_in[8];
    const float* lin_b      = (const float*)d_in[9];
    const int* edge_index   = (const int*)d_in[10];
    const int* node2graph   = (const int*)d_in[11];

    const int N = in_sizes[0] / NODE_DIM;     // 100000
    const int B = in_sizes[1] / COND_DIM;     // 64
    const int E = in_sizes[10] / 2;           // 1600000
    const int NB = (N + 1023) / 1024;

    auto align_up = [](size_t x) { return (x + 255) & ~(size_t)255; };
    char* ws = (char*)d_ws;
    size_t off = 0;
    int* deg        = (int*)(ws + off); off += align_up((size_t)N * 4);
    int* cursor     = (int*)(ws + off); off += align_up((size_t)N * 4);
    const size_t zero_bytes = off;            // deg + cursor zeroed
    int* csr_off    = (int*)(ws + off); off += align_up((size_t)(N + 1) * 4);
    int* bsums      = (int*)(ws + off); off += align_up(1024 * 4);
    int* boff       = (int*)(ws + off); off += align_up(1024 * 4);
    int* bucket_src = (int*)(ws + off); off += align_up((size_t)E * 4);
    unsigned short* x_mid = (unsigned short*)(ws + off); off += align_up((size_t)N * OUT_DIM * 2);
    float* gamma    = (float*)(ws + off); off += align_up((size_t)B * HID * 4);
    float* beta     = (float*)(ws + off); off += align_up((size_t)B * HID * 4);
    short* wlin_bf  = (short*)(ws + off); off += align_up((size_t)OUT_DIM * HID * 2);
    short* fw_bf    = (short*)(ws + off); off += align_up((size_t)HID * NODE_DIM * 2);

    hipMemsetAsync(d_ws, 0, zero_bytes, stream);

    prep<<<130, 256, 0, stream>>>(cond_feats, cond_w_v, cond_w_g, cond_b,
                                  lin_w_v, lin_w_g, film_w,
                                  gamma, beta, wlin_bf, fw_bf, B);

    deg_count<<<(E + 255) / 256, 256, 0, stream>>>(edge_index, deg, E);
    scan1<<<NB, 1024, 0, stream>>>(deg, csr_off, bsums, N);
    scan2<<<1, 1024, 0, stream>>>(bsums, boff, NB);
    scan3<<<NB, 1024, 0, stream>>>(csr_off, boff, N);
    bucket_fill<<<(E + 255) / 256, 256, 0, stream>>>(edge_index, csr_off,
                                                     cursor, bucket_src, E);

    node_film_mfma<<<(N + 63) / 64, 256, 0, stream>>>(
        node_feats, fw_bf, film_b, lin_b, gamma, beta, wlin_bf, node2graph,
        x_mid, N);

    edge_aggregate<<<(N + 3) / 4, 256, 0, stream>>>(csr_off, bucket_src,
                                                    x_mid, (float*)d_out, N);
}